// Round 1
// baseline (467.180 us; speedup 1.0000x reference)
//
#include <hip/hip_runtime.h>
#include <hip/hip_bf16.h>

typedef short bf16x8 __attribute__((ext_vector_type(8)));
typedef float f32x4 __attribute__((ext_vector_type(4)));
typedef unsigned short ushort_t;

#define NH 16
#define HD 128
#define SEQ 2048
#define HID 2048
#define NQKV 6144
#define BATCH 2

__device__ __forceinline__ ushort_t f2bf(float x) {
    unsigned u = __builtin_bit_cast(unsigned, x);
    u = (u + 0x7fffu + ((u >> 16) & 1u)) >> 16;
    return (ushort_t)u;
}

// async global->LDS, 16B per lane. LDS dest = wave-uniform base + lane*16.
__device__ __forceinline__ void gl2lds16(const ushort_t* g, ushort_t* l) {
    __builtin_amdgcn_global_load_lds(
        (__attribute__((address_space(1))) void*)(g),
        (__attribute__((address_space(3))) void*)(l), 16, 0, 0);
}

// ---------------------------------------------------------------------------
// fp32 -> bf16 elementwise (hidden states), 8 elems/thread
// ---------------------------------------------------------------------------
__global__ __launch_bounds__(256) void to_bf16(
    const float* __restrict__ x, ushort_t* __restrict__ y, int n8) {
    int i = blockIdx.x * 256 + threadIdx.x;
    if (i >= n8) return;
    float4 a0 = *(const float4*)(x + (size_t)i * 8);
    float4 a1 = *(const float4*)(x + (size_t)i * 8 + 4);
    union { ushort_t u[8]; uint4 v; } p;
    p.u[0]=f2bf(a0.x); p.u[1]=f2bf(a0.y); p.u[2]=f2bf(a0.z); p.u[3]=f2bf(a0.w);
    p.u[4]=f2bf(a1.x); p.u[5]=f2bf(a1.y); p.u[6]=f2bf(a1.z); p.u[7]=f2bf(a1.w);
    *(uint4*)(y + (size_t)i * 8) = p.v;
}

// ---------------------------------------------------------------------------
// Transpose + fp32->bf16: w [K][N] -> wT [N][K] bf16
// ---------------------------------------------------------------------------
__global__ __launch_bounds__(256) void transpose_to_bf16(
    const float* __restrict__ w, ushort_t* __restrict__ wT, int K, int N) {
    __shared__ float tile[32][33];
    int nb = blockIdx.x * 32, kb = blockIdx.y * 32;
    int tx = threadIdx.x, ty = threadIdx.y;  // 32 x 8
#pragma unroll
    for (int i = 0; i < 4; ++i) {
        int k = kb + ty + i * 8;
        tile[ty + i * 8][tx] = w[(size_t)k * N + nb + tx];
    }
    __syncthreads();
#pragma unroll
    for (int i = 0; i < 4; ++i) {
        int n = nb + ty + i * 8;
        wT[(size_t)n * K + kb + tx] = f2bf(tile[tx][ty + i * 8]);
    }
}

// ---------------------------------------------------------------------------
// m97-style GEMM core: 128x128 tile, BK=64, global_load_lds(16B) staging with
// XOR-swizzled chunk order. LDS[r][slot s] holds global k-chunk s^(r&7).
// ---------------------------------------------------------------------------
#define GEMM_KLOOP(A_, BT_)                                                     \
    const int t = threadIdx.x;                                                  \
    const int w = t >> 6, lane = t & 63, lm = lane & 15, lq = lane >> 4;        \
    const int wm = (w >> 1) * 64, wn = (w & 1) * 64;                            \
    const int lrow = lane >> 3, lsw = (lane & 7) ^ lrow;                        \
    f32x4 acc[4][4] = {};                                                       \
    const ushort_t* gA = A_ + (size_t)(mb + w * 32 + lrow) * HID + lsw * 8;     \
    const ushort_t* gB = BT_ + (size_t)(nb + w * 32 + lrow) * HID + lsw * 8;    \
    for (int kb = 0; kb < HID; kb += 64) {                                      \
        __syncthreads();                                                        \
        _Pragma("unroll")                                                       \
        for (int c = 0; c < 4; ++c) {                                           \
            gl2lds16(gA + (size_t)c * 8 * HID + kb, At + (w * 256 + c * 64) * 8); \
            gl2lds16(gB + (size_t)c * 8 * HID + kb, Bt + (w * 256 + c * 64) * 8); \
        }                                                                       \
        __syncthreads();                                                        \
        _Pragma("unroll")                                                       \
        for (int kc = 0; kc < 2; ++kc) {                                        \
            const int slot = (kc * 4 + lq) ^ (lm & 7);                          \
            bf16x8 af[4], bfr[4];                                               \
            _Pragma("unroll")                                                   \
            for (int mt = 0; mt < 4; ++mt)                                      \
                af[mt] = ((const bf16x8*)At)[(wm + mt * 16 + lm) * 8 + slot];   \
            _Pragma("unroll")                                                   \
            for (int nt = 0; nt < 4; ++nt)                                      \
                bfr[nt] = ((const bf16x8*)Bt)[(wn + nt * 16 + lm) * 8 + slot];  \
            _Pragma("unroll")                                                   \
            for (int mt = 0; mt < 4; ++mt)                                      \
                _Pragma("unroll")                                               \
                for (int nt = 0; nt < 4; ++nt)                                  \
                    acc[mt][nt] = __builtin_amdgcn_mfma_f32_16x16x32_bf16(      \
                        af[mt], bfr[nt], acc[mt][nt], 0, 0, 0);                 \
        }                                                                       \
    }

// ---------------------------------------------------------------------------
// GEMM 1: qkv = hidden(bf16) @ w_qkv + b_qkv
// q,k -> [B,nh,S,hd]; v -> vT [B,nh,hd,S] via in-LDS transpose (tile = 128 s
// x one head's 128 d), coalesced 16B writes.
// ---------------------------------------------------------------------------
__global__ __launch_bounds__(256) void gemm_qkv(
    const ushort_t* __restrict__ A, const ushort_t* __restrict__ BT,
    const float* __restrict__ bias,
    ushort_t* __restrict__ qbuf, ushort_t* __restrict__ kbuf,
    ushort_t* __restrict__ vTbuf) {
    __shared__ unsigned shbuf[128 * 68];  // 34KB: staging (32KB) / transpose T
    ushort_t* At = (ushort_t*)shbuf;
    ushort_t* Bt = At + 128 * 64;
    const int mb = blockIdx.x * 128;
    const int nb = blockIdx.y * 128;
    GEMM_KLOOP(A, BT)

    const int sec = nb >> 11;
    if (sec < 2) {
        // q/k: direct scatter (coalesced in d across lm)
#pragma unroll
        for (int mt = 0; mt < 4; ++mt)
#pragma unroll
            for (int nt = 0; nt < 4; ++nt)
#pragma unroll
                for (int r = 0; r < 4; ++r) {
                    int m = mb + wm + mt * 16 + lq * 4 + r;
                    int c = nb + wn + nt * 16 + lm;
                    float val = acc[mt][nt][r] + bias[c];
                    int h = (c >> 7) & 15;
                    int d = c & 127;
                    int b = m >> 11, s = m & 2047;
                    size_t bh = (size_t)(b * NH + h);
                    ushort_t* dst = (sec == 0) ? qbuf : kbuf;
                    dst[(bh * SEQ + s) * HD + d] = f2bf(val);
                }
    } else {
        // v: transpose in LDS, write vT[bh][d][s] coalesced
        __syncthreads();  // all waves done reading staging LDS
        unsigned* T = shbuf;  // [c(128)][68 uints], uint idx = c*68 + m/2
#pragma unroll
        for (int mt = 0; mt < 4; ++mt)
#pragma unroll
            for (int nt = 0; nt < 4; ++nt) {
                const int cl = wn + nt * 16 + lm;       // d 0..127
                const int ml = wm + mt * 16 + lq * 4;   // s-local base
                const float bb = bias[nb + cl];
#pragma unroll
                for (int r = 0; r < 4; r += 2) {
                    unsigned pk = (unsigned)f2bf(acc[mt][nt][r] + bb) |
                                  ((unsigned)f2bf(acc[mt][nt][r + 1] + bb) << 16);
                    T[cl * 68 + ((ml + r) >> 1)] = pk;
                }
            }
        __syncthreads();
        const int d = t & 127, sh = t >> 7;
        const int b = mb >> 11, sbase = mb & 2047;
        const int hv = (nb >> 7) - 32;
        ushort_t* vrow = vTbuf + ((size_t)(b * NH + hv) * HD + d) * SEQ + sbase + sh * 64;
#pragma unroll
        for (int i = 0; i < 8; ++i)
            *(uint4*)(vrow + i * 8) = *(const uint4*)&T[d * 68 + sh * 32 + i * 4];
    }
}

// GEMM 2: out = attn(bf16) @ w_proj + b_proj -> fp32
__global__ __launch_bounds__(256) void gemm_proj(
    const ushort_t* __restrict__ A, const ushort_t* __restrict__ BT,
    const float* __restrict__ bias, float* __restrict__ out) {
    __shared__ ushort_t Abuf[128 * 64];
    __shared__ ushort_t Bbuf[128 * 64];
    ushort_t* At = Abuf;
    ushort_t* Bt = Bbuf;
    const int mb = blockIdx.x * 128;
    const int nb = blockIdx.y * 128;
    GEMM_KLOOP(A, BT)
#pragma unroll
    for (int mt = 0; mt < 4; ++mt)
#pragma unroll
        for (int nt = 0; nt < 4; ++nt)
#pragma unroll
            for (int r = 0; r < 4; ++r) {
                int m = mb + wm + mt * 16 + lq * 4 + r;
                int c = nb + wn + nt * 16 + lm;
                out[(size_t)m * HID + c] = acc[mt][nt][r] + bias[c];
            }
}

// ---------------------------------------------------------------------------
// Flash attention, S^T = K Q^T. Grid 1024. XCD-pinned block mapping:
//   bid = g*8 + (bh&7), g = (31-qt)*4 + (bh>>3)
// -> all 32 q-tile blocks of one (b,h) share bid%8 (same XCD) so K/V stay in
// that XCD's L2. qt descending (LPT).
// Async reg-staged K/V: loads for tile kt+1 issued during compute of tile kt
// (global->reg->ds_write, T14 async-STAGE split). Same XOR-swizzled LDS
// layout as before (swizzle folded into the per-thread global source addr).
// + s_setprio around MFMA clusters (T5), defer-max rescale skip (T13, THR=8).
// ---------------------------------------------------------------------------
__global__ __launch_bounds__(256) void attn_kernel(
    const ushort_t* __restrict__ qb, const ushort_t* __restrict__ kbuf,
    const ushort_t* __restrict__ vT, ushort_t* __restrict__ ob) {
    __shared__ ushort_t Ks[64 * 128];   // [key][d] swizzled 16B chunks
    __shared__ ushort_t Vs[128 * 64];   // [d][key] swizzled 16B chunks
    __shared__ ushort_t Ps[4][16 * 72]; // per-wave P, row stride 72

    const int bid = blockIdx.x;
    const int x = bid & 7, g = bid >> 3;
    const int qt = 31 - (g >> 2);
    const int bh = ((g & 3) << 3) | x;
    const int qbase = qt * 64;
    const int t = threadIdx.x, w = t >> 6, lane = t & 63;
    const int lm = lane & 15, lq = lane >> 4;

    const ushort_t* Qg = qb + (size_t)bh * SEQ * HD;
    const ushort_t* Kg = kbuf + (size_t)bh * SEQ * HD;
    const ushort_t* Vg = vT + (size_t)bh * HD * SEQ;

    const float LOG2E = 1.44269504f;
    const int h = bh & 15;
    const float slope2 = exp2f(-0.5f * (float)(h + 1)) * LOG2E;
    const float scale2 = (1.0f / 128.0f) * LOG2E;

    const int qg = qbase + w * 16 + lm;  // this lane's q row

    // Q fragments direct from global (B-operand layout)
    bf16x8 qf[4];
#pragma unroll
    for (int kc = 0; kc < 4; ++kc) {
        uint4 qv = *(const uint4*)(Qg + (size_t)qg * HD + kc * 32 + lq * 8);
        qf[kc] = __builtin_bit_cast(bf16x8, qv);
    }

    float foff[4][4];
#pragma unroll
    for (int mt = 0; mt < 4; ++mt)
#pragma unroll
        for (int r = 0; r < 4; ++r)
            foff[mt][r] = slope2 * (float)(mt * 16 + lq * 4 + r);

    // per-thread swizzled staging source offsets (same layout as the old
    // global_load_lds path: LDS linear pos ci=i*256+t holds K chunk
    // (ks&8)|((ks&7)^(kr&7)) of row kr, V chunk vs^(vr&7) of row vr)
    int koffs[4], voffs[4];
#pragma unroll
    for (int i = 0; i < 4; ++i) {
        int ci = i * 256 + t;
        int kr = ci >> 4, ks = ci & 15;
        int kcg = (ks & 8) | ((ks & 7) ^ (kr & 7));
        koffs[i] = kr * HD + kcg * 8;
        int vr = ci >> 3, vs = ci & 7;
        int vcg = vs ^ (vr & 7);
        voffs[i] = vr * SEQ + vcg * 8;
    }

    float mrow = -1e30f, lrow = 0.0f;
    f32x4 O[8] = {};
    const int nkt = qt + 1;

    // prologue: issue loads for kt=0
    const ushort_t* Kt = Kg;
    const ushort_t* Vt = Vg;
    uint4 kreg[4], vreg[4];
#pragma unroll
    for (int i = 0; i < 4; ++i) {
        kreg[i] = *(const uint4*)(Kt + koffs[i]);
        vreg[i] = *(const uint4*)(Vt + voffs[i]);
    }

    for (int kt = 0; kt < nkt; ++kt) {
        __syncthreads();  // prev iteration's LDS reads done
        // write staged K/V regs -> LDS (linear thread order, swizzle already
        // applied on the global source side)
#pragma unroll
        for (int i = 0; i < 4; ++i) {
            *(uint4*)&Ks[(i * 256 + t) * 8] = kreg[i];
            *(uint4*)&Vs[(i * 256 + t) * 8] = vreg[i];
        }
        // issue next tile's loads: latency hides under this tile's compute
        if (kt + 1 < nkt) {
            Kt += 64 * HD;
            Vt += 64;
#pragma unroll
            for (int i = 0; i < 4; ++i) {
                kreg[i] = *(const uint4*)(Kt + koffs[i]);
                vreg[i] = *(const uint4*)(Vt + voffs[i]);
            }
        }
        __syncthreads();  // staging visible

        // S^T = K Q^T : per wave 64 keys x 16 q
        f32x4 sacc[4] = {};
        __builtin_amdgcn_s_setprio(1);
#pragma unroll
        for (int kc = 0; kc < 4; ++kc) {
            const int slot = ((kc * 4 + lq) & 8) | (((kc * 4 + lq) & 7) ^ (lm & 7));
#pragma unroll
            for (int mt = 0; mt < 4; ++mt) {
                bf16x8 bk = *(const bf16x8*)&Ks[((mt * 16 + lm) * 16 + slot) * 8];
                sacc[mt] = __builtin_amdgcn_mfma_f32_16x16x32_bf16(bk, qf[kc], sacc[mt], 0, 0, 0);
            }
        }
        __builtin_amdgcn_s_setprio(0);

        // scores (log2 domain); mask only on the diagonal tile
        const float sbase = slope2 * (float)(kt * 64 - qg);
        float sc[4][4];
        if (kt == qt) {
#pragma unroll
            for (int mt = 0; mt < 4; ++mt)
#pragma unroll
                for (int r = 0; r < 4; ++r) {
                    float s = sacc[mt][r] * scale2 + (sbase + foff[mt][r]);
                    sc[mt][r] = (kt * 64 + mt * 16 + lq * 4 + r <= qg) ? s : -3e38f;
                }
        } else {
#pragma unroll
            for (int mt = 0; mt < 4; ++mt)
#pragma unroll
                for (int r = 0; r < 4; ++r)
                    sc[mt][r] = sacc[mt][r] * scale2 + (sbase + foff[mt][r]);
        }

        // row max: 15 in-lane + 2 shuffles
        float tm = sc[0][0];
#pragma unroll
        for (int mt = 0; mt < 4; ++mt)
#pragma unroll
            for (int r = 0; r < 4; ++r) tm = fmaxf(tm, sc[mt][r]);
        tm = fmaxf(tm, __shfl_xor(tm, 16));
        tm = fmaxf(tm, __shfl_xor(tm, 32));

        // defer-max (T13): if no row's max grew by >8 (log2), keep old max and
        // skip the O-rescale entirely (P bounded by 2^8 -> fine in bf16).
        const bool noresc = __all(tm <= mrow + 8.0f) && (kt > 0);
        float mnew, alpha;
        if (noresc) {
            mnew = mrow;
            alpha = 1.0f;
        } else {
            mnew = fmaxf(mrow, tm);
            alpha = __builtin_amdgcn_exp2f(mrow - mnew);
        }
        mrow = mnew;

        // p = exp2(sc - m) -> Ps[q][key], sum
        float psum = 0.0f;
#pragma unroll
        for (int mt = 0; mt < 4; ++mt) {
            float p0 = __builtin_amdgcn_exp2f(sc[mt][0] - mnew);
            float p1 = __builtin_amdgcn_exp2f(sc[mt][1] - mnew);
            float p2 = __builtin_amdgcn_exp2f(sc[mt][2] - mnew);
            float p3 = __builtin_amdgcn_exp2f(sc[mt][3] - mnew);
            psum += (p0 + p1) + (p2 + p3);
            uint2 wv;
            wv.x = ((unsigned)f2bf(p1) << 16) | f2bf(p0);
            wv.y = ((unsigned)f2bf(p3) << 16) | f2bf(p2);
            *(uint2*)&Ps[w][lm * 72 + mt * 16 + lq * 4] = wv;
        }
        psum += __shfl_xor(psum, 16);
        psum += __shfl_xor(psum, 32);
        lrow = lrow * alpha + psum;

        // rescale O (skipped when deferred; branch is wave-uniform)
        if (!noresc) {
            float av[4];
#pragma unroll
            for (int r = 0; r < 4; ++r) av[r] = __shfl(alpha, lq * 4 + r);
#pragma unroll
            for (int nt = 0; nt < 8; ++nt)
#pragma unroll
                for (int r = 0; r < 4; ++r) O[nt][r] *= av[r];
        }

        // PV: A = P (q=lane&15), B = V^T (swizzled)
        asm volatile("s_waitcnt lgkmcnt(0)" ::: "memory");
        __builtin_amdgcn_s_setprio(1);
#pragma unroll
        for (int kc2 = 0; kc2 < 2; ++kc2) {
            bf16x8 ap = *(const bf16x8*)&Ps[w][lm * 72 + kc2 * 32 + lq * 8];
            const int slot = (kc2 * 4 + lq) ^ (lm & 7);
#pragma unroll
            for (int nt = 0; nt < 8; ++nt) {
                bf16x8 bv = *(const bf16x8*)&Vs[((nt * 16 + lm) * 8 + slot) * 8];
                O[nt] = __builtin_amdgcn_mfma_f32_16x16x32_bf16(ap, bv, O[nt], 0, 0, 0);
            }
        }
        __builtin_amdgcn_s_setprio(0);
    }

    // epilogue
    float lb[4];
#pragma unroll
    for (int r = 0; r < 4; ++r)
        lb[r] = __builtin_amdgcn_rcpf(__shfl(lrow, lq * 4 + r));
    const int b = bh >> 4;
#pragma unroll
    for (int nt = 0; nt < 8; ++nt)
#pragma unroll
        for (int r = 0; r < 4; ++r) {
            int s = qbase + w * 16 + lq * 4 + r;
            int d = nt * 16 + lm;
            ob[((size_t)(b * SEQ + s)) * HID + h * HD + d] = f2bf(O[nt][r] * lb[r]);
        }
}

// ---------------------------------------------------------------------------
extern "C" void kernel_launch(void* const* d_in, const int* in_sizes, int n_in,
                              void* d_out, int out_size, void* d_ws, size_t ws_size,
                              hipStream_t stream) {
    const float* hidden = (const float*)d_in[0];
    const float* w_qkv = (const float*)d_in[1];
    const float* b_qkv = (const float*)d_in[2];
    const float* w_proj = (const float*)d_in[3];
    const float* b_proj = (const float*)d_in[4];
    float* out = (float*)d_out;

    char* ws = (char*)d_ws;
    size_t off = 0;
    ushort_t* wqkvT = (ushort_t*)(ws + off); off += (size_t)NQKV * HID * 2;
    ushort_t* wprojT = (ushort_t*)(ws + off); off += (size_t)HID * HID * 2;
    ushort_t* hbf = (ushort_t*)(ws + off); off += (size_t)BATCH * SEQ * HID * 2;
    ushort_t* qw = (ushort_t*)(ws + off); off += (size_t)BATCH * NH * SEQ * HD * 2;
    ushort_t* kw = (ushort_t*)(ws + off); off += (size_t)BATCH * NH * SEQ * HD * 2;
    ushort_t* vTw = (ushort_t*)(ws + off); off += (size_t)BATCH * NH * SEQ * HD * 2;
    ushort_t* attnw = (ushort_t*)(ws + off); off += (size_t)BATCH * SEQ * HID * 2;

    to_bf16<<<dim3(BATCH * SEQ * HID / 8 / 256), 256, 0, stream>>>(
        hidden, hbf, BATCH * SEQ * HID / 8);
    transpose_to_bf16<<<dim3(NQKV / 32, HID / 32), dim3(32, 8), 0, stream>>>(
        w_qkv, wqkvT, HID, NQKV);
    transpose_to_bf16<<<dim3(HID / 32, HID / 32), dim3(32, 8), 0, stream>>>(
        w_proj, wprojT, HID, HID);

    gemm_qkv<<<dim3(BATCH * SEQ / 128, NQKV / 128), 256, 0, stream>>>(
        hbf, wqkvT, b_qkv, qw, kw, vTw);

    attn_kernel<<<dim3(BATCH * NH * 32), 256, 0, stream>>>(qw, kw, vTw, attnw);

    gemm_proj<<<dim3(BATCH * SEQ / 128, HID / 128), 256, 0, stream>>>(
        attnw, wprojT, b_proj, out);
}

// Round 2
// 364.418 us; speedup vs baseline: 1.2820x; 1.2820x over previous
//
#include <hip/hip_runtime.h>
#include <hip/hip_bf16.h>

typedef short bf16x8 __attribute__((ext_vector_type(8)));
typedef float f32x4 __attribute__((ext_vector_type(4)));
typedef unsigned short ushort_t;

#define NH 16
#define HD 128
#define SEQ 2048
#define HID 2048
#define NQKV 6144
#define BATCH 2

__device__ __forceinline__ ushort_t f2bf(float x) {
    unsigned u = __builtin_bit_cast(unsigned, x);
    u = (u + 0x7fffu + ((u >> 16) & 1u)) >> 16;
    return (ushort_t)u;
}

// async global->LDS, 16B per lane. LDS dest = wave-uniform base + lane*16.
__device__ __forceinline__ void gl2lds16(const ushort_t* g, ushort_t* l) {
    __builtin_amdgcn_global_load_lds(
        (__attribute__((address_space(1))) void*)(g),
        (__attribute__((address_space(3))) void*)(l), 16, 0, 0);
}

// ---------------------------------------------------------------------------
// fp32 -> bf16 elementwise (hidden states), 8 elems/thread
// ---------------------------------------------------------------------------
__global__ __launch_bounds__(256) void to_bf16(
    const float* __restrict__ x, ushort_t* __restrict__ y, int n8) {
    int i = blockIdx.x * 256 + threadIdx.x;
    if (i >= n8) return;
    float4 a0 = *(const float4*)(x + (size_t)i * 8);
    float4 a1 = *(const float4*)(x + (size_t)i * 8 + 4);
    union { ushort_t u[8]; uint4 v; } p;
    p.u[0]=f2bf(a0.x); p.u[1]=f2bf(a0.y); p.u[2]=f2bf(a0.z); p.u[3]=f2bf(a0.w);
    p.u[4]=f2bf(a1.x); p.u[5]=f2bf(a1.y); p.u[6]=f2bf(a1.z); p.u[7]=f2bf(a1.w);
    *(uint4*)(y + (size_t)i * 8) = p.v;
}

// ---------------------------------------------------------------------------
// Transpose + fp32->bf16: w [K][N] -> wT [N][K] bf16
// ---------------------------------------------------------------------------
__global__ __launch_bounds__(256) void transpose_to_bf16(
    const float* __restrict__ w, ushort_t* __restrict__ wT, int K, int N) {
    __shared__ float tile[32][33];
    int nb = blockIdx.x * 32, kb = blockIdx.y * 32;
    int tx = threadIdx.x, ty = threadIdx.y;  // 32 x 8
#pragma unroll
    for (int i = 0; i < 4; ++i) {
        int k = kb + ty + i * 8;
        tile[ty + i * 8][tx] = w[(size_t)k * N + nb + tx];
    }
    __syncthreads();
#pragma unroll
    for (int i = 0; i < 4; ++i) {
        int n = nb + ty + i * 8;
        wT[(size_t)n * K + kb + tx] = f2bf(tile[tx][ty + i * 8]);
    }
}

// ---------------------------------------------------------------------------
// m97-style GEMM core: 128x128 tile, BK=64, global_load_lds(16B) staging with
// XOR-swizzled chunk order. LDS[r][slot s] holds global k-chunk s^(r&7).
// ---------------------------------------------------------------------------
#define GEMM_KLOOP(A_, BT_)                                                     \
    const int t = threadIdx.x;                                                  \
    const int w = t >> 6, lane = t & 63, lm = lane & 15, lq = lane >> 4;        \
    const int wm = (w >> 1) * 64, wn = (w & 1) * 64;                            \
    const int lrow = lane >> 3, lsw = (lane & 7) ^ lrow;                        \
    f32x4 acc[4][4] = {};                                                       \
    const ushort_t* gA = A_ + (size_t)(mb + w * 32 + lrow) * HID + lsw * 8;     \
    const ushort_t* gB = BT_ + (size_t)(nb + w * 32 + lrow) * HID + lsw * 8;    \
    for (int kb = 0; kb < HID; kb += 64) {                                      \
        __syncthreads();                                                        \
        _Pragma("unroll")                                                       \
        for (int c = 0; c < 4; ++c) {                                           \
            gl2lds16(gA + (size_t)c * 8 * HID + kb, At + (w * 256 + c * 64) * 8); \
            gl2lds16(gB + (size_t)c * 8 * HID + kb, Bt + (w * 256 + c * 64) * 8); \
        }                                                                       \
        __syncthreads();                                                        \
        _Pragma("unroll")                                                       \
        for (int kc = 0; kc < 2; ++kc) {                                        \
            const int slot = (kc * 4 + lq) ^ (lm & 7);                          \
            bf16x8 af[4], bfr[4];                                               \
            _Pragma("unroll")                                                   \
            for (int mt = 0; mt < 4; ++mt)                                      \
                af[mt] = ((const bf16x8*)At)[(wm + mt * 16 + lm) * 8 + slot];   \
            _Pragma("unroll")                                                   \
            for (int nt = 0; nt < 4; ++nt)                                      \
                bfr[nt] = ((const bf16x8*)Bt)[(wn + nt * 16 + lm) * 8 + slot];  \
            _Pragma("unroll")                                                   \
            for (int mt = 0; mt < 4; ++mt)                                      \
                _Pragma("unroll")                                               \
                for (int nt = 0; nt < 4; ++nt)                                  \
                    acc[mt][nt] = __builtin_amdgcn_mfma_f32_16x16x32_bf16(      \
                        af[mt], bfr[nt], acc[mt][nt], 0, 0, 0);                 \
        }                                                                       \
    }

// ---------------------------------------------------------------------------
// GEMM 1: qkv = hidden(bf16) @ w_qkv + b_qkv
// q,k -> [B,nh,S,hd]; v -> vT [B,nh,hd,S] via in-LDS transpose (tile = 128 s
// x one head's 128 d), coalesced 16B writes.
// ---------------------------------------------------------------------------
__global__ __launch_bounds__(256) void gemm_qkv(
    const ushort_t* __restrict__ A, const ushort_t* __restrict__ BT,
    const float* __restrict__ bias,
    ushort_t* __restrict__ qbuf, ushort_t* __restrict__ kbuf,
    ushort_t* __restrict__ vTbuf) {
    __shared__ unsigned shbuf[128 * 68];  // 34KB: staging (32KB) / transpose T
    ushort_t* At = (ushort_t*)shbuf;
    ushort_t* Bt = At + 128 * 64;
    const int mb = blockIdx.x * 128;
    const int nb = blockIdx.y * 128;
    GEMM_KLOOP(A, BT)

    const int sec = nb >> 11;
    if (sec < 2) {
        // q/k: direct scatter (coalesced in d across lm)
#pragma unroll
        for (int mt = 0; mt < 4; ++mt)
#pragma unroll
            for (int nt = 0; nt < 4; ++nt)
#pragma unroll
                for (int r = 0; r < 4; ++r) {
                    int m = mb + wm + mt * 16 + lq * 4 + r;
                    int c = nb + wn + nt * 16 + lm;
                    float val = acc[mt][nt][r] + bias[c];
                    int h = (c >> 7) & 15;
                    int d = c & 127;
                    int b = m >> 11, s = m & 2047;
                    size_t bh = (size_t)(b * NH + h);
                    ushort_t* dst = (sec == 0) ? qbuf : kbuf;
                    dst[(bh * SEQ + s) * HD + d] = f2bf(val);
                }
    } else {
        // v: transpose in LDS, write vT[bh][d][s] coalesced
        __syncthreads();  // all waves done reading staging LDS
        unsigned* T = shbuf;  // [c(128)][68 uints], uint idx = c*68 + m/2
#pragma unroll
        for (int mt = 0; mt < 4; ++mt)
#pragma unroll
            for (int nt = 0; nt < 4; ++nt) {
                const int cl = wn + nt * 16 + lm;       // d 0..127
                const int ml = wm + mt * 16 + lq * 4;   // s-local base
                const float bb = bias[nb + cl];
#pragma unroll
                for (int r = 0; r < 4; r += 2) {
                    unsigned pk = (unsigned)f2bf(acc[mt][nt][r] + bb) |
                                  ((unsigned)f2bf(acc[mt][nt][r + 1] + bb) << 16);
                    T[cl * 68 + ((ml + r) >> 1)] = pk;
                }
            }
        __syncthreads();
        const int d = t & 127, sh = t >> 7;
        const int b = mb >> 11, sbase = mb & 2047;
        const int hv = (nb >> 7) - 32;
        ushort_t* vrow = vTbuf + ((size_t)(b * NH + hv) * HD + d) * SEQ + sbase + sh * 64;
#pragma unroll
        for (int i = 0; i < 8; ++i)
            *(uint4*)(vrow + i * 8) = *(const uint4*)&T[d * 68 + sh * 32 + i * 4];
    }
}

// GEMM 2: out = attn(bf16) @ w_proj + b_proj -> fp32
__global__ __launch_bounds__(256) void gemm_proj(
    const ushort_t* __restrict__ A, const ushort_t* __restrict__ BT,
    const float* __restrict__ bias, float* __restrict__ out) {
    __shared__ ushort_t Abuf[128 * 64];
    __shared__ ushort_t Bbuf[128 * 64];
    ushort_t* At = Abuf;
    ushort_t* Bt = Bbuf;
    const int mb = blockIdx.x * 128;
    const int nb = blockIdx.y * 128;
    GEMM_KLOOP(A, BT)
#pragma unroll
    for (int mt = 0; mt < 4; ++mt)
#pragma unroll
        for (int nt = 0; nt < 4; ++nt)
#pragma unroll
            for (int r = 0; r < 4; ++r) {
                int m = mb + wm + mt * 16 + lq * 4 + r;
                int c = nb + wn + nt * 16 + lm;
                out[(size_t)m * HID + c] = acc[mt][nt][r] + bias[c];
            }
}

// ---------------------------------------------------------------------------
// Flash attention, S^T = K Q^T. Grid 1024. XCD-pinned block mapping:
//   bid = g*8 + (bh&7), g = (31-qt)*4 + (bh>>3)
// -> all 32 q-tile blocks of one (b,h) share bid%8 (same XCD) so K/V stay in
// that XCD's L2. qt descending (LPT).
//
// Round-2 structure: DOUBLE-BUFFERED global_load_lds staging (T3 minimum
// 2-phase recipe). Per iteration: issue DMA for tile kt+1 into buf^1, compute
// tile kt from buf, then ONE __syncthreads (its implicit vmcnt(0) drain lands
// AFTER the compute phase, so the DMA latency hides under QK+softmax+PV).
// Zero register cost for staging (round-1's reg-staging spilled to scratch:
// WRITE_SIZE 355MB, MfmaUtil 7.3%). LDS 73KB -> 2 blocks/CU.
// + s_setprio around MFMA clusters (T5), defer-max rescale skip (T13, THR=8).
// ---------------------------------------------------------------------------
__global__ __launch_bounds__(256) void attn_kernel(
    const ushort_t* __restrict__ qb, const ushort_t* __restrict__ kbuf,
    const ushort_t* __restrict__ vT, ushort_t* __restrict__ ob) {
    __shared__ ushort_t Ks[2][64 * 128];   // [key][d] swizzled 16B chunks
    __shared__ ushort_t Vs[2][128 * 64];   // [d][key] swizzled 16B chunks
    __shared__ ushort_t Ps[4][16 * 72];    // per-wave P, row stride 72

    const int bid = blockIdx.x;
    const int x = bid & 7, g = bid >> 3;
    const int qt = 31 - (g >> 2);
    const int bh = ((g & 3) << 3) | x;
    const int qbase = qt * 64;
    const int t = threadIdx.x, w = t >> 6, lane = t & 63;
    const int lm = lane & 15, lq = lane >> 4;

    const ushort_t* Qg = qb + (size_t)bh * SEQ * HD;
    const ushort_t* Kg = kbuf + (size_t)bh * SEQ * HD;
    const ushort_t* Vg = vT + (size_t)bh * HD * SEQ;

    const float LOG2E = 1.44269504f;
    const int h = bh & 15;
    const float slope2 = exp2f(-0.5f * (float)(h + 1)) * LOG2E;
    const float scale2 = (1.0f / 128.0f) * LOG2E;

    const int qg = qbase + w * 16 + lm;  // this lane's q row

    // Q fragments direct from global (B-operand layout)
    bf16x8 qf[4];
#pragma unroll
    for (int kc = 0; kc < 4; ++kc) {
        uint4 qv = *(const uint4*)(Qg + (size_t)qg * HD + kc * 32 + lq * 8);
        qf[kc] = __builtin_bit_cast(bf16x8, qv);
    }

    float foff[4][4];
#pragma unroll
    for (int mt = 0; mt < 4; ++mt)
#pragma unroll
        for (int r = 0; r < 4; ++r)
            foff[mt][r] = slope2 * (float)(mt * 16 + lq * 4 + r);

    // per-thread swizzled DMA source offsets. LDS linear pos ci=i*256+t holds
    // K chunk (ks&8)|((ks&7)^(kr&7)) of key-row kr, V chunk vs^(vr&7) of
    // d-row vr (matches the swizzled read pattern in the MFMA loops).
    int koffs[4], voffs[4];
#pragma unroll
    for (int i = 0; i < 4; ++i) {
        int ci = i * 256 + t;
        int kr = ci >> 4, ks = ci & 15;
        int kcg = (ks & 8) | ((ks & 7) ^ (kr & 7));
        koffs[i] = kr * HD + kcg * 8;
        int vr = ci >> 3, vs = ci & 7;
        int vcg = vs ^ (vr & 7);
        voffs[i] = vr * SEQ + vcg * 8;
    }

#define ATTN_STAGE(KT, BUF)                                                   \
    {                                                                         \
        const ushort_t* Kt_ = Kg + (size_t)(KT) * 64 * HD;                    \
        const ushort_t* Vt_ = Vg + (size_t)(KT) * 64;                         \
        _Pragma("unroll")                                                     \
        for (int i = 0; i < 4; ++i) {                                         \
            gl2lds16(Kt_ + koffs[i], Ks[BUF] + (i * 256 + w * 64) * 8);       \
            gl2lds16(Vt_ + voffs[i], Vs[BUF] + (i * 256 + w * 64) * 8);       \
        }                                                                     \
    }

    float mrow = -1e30f, lrow = 0.0f;
    f32x4 O[8] = {};
    const int nkt = qt + 1;

    // prologue: stage tile 0, drain, sync
    ATTN_STAGE(0, 0)
    __syncthreads();

    for (int kt = 0; kt < nkt; ++kt) {
        const int cur = kt & 1;
        // issue next tile's DMA into the other buffer (all waves finished
        // reading it at the previous barrier); latency hides under compute
        if (kt + 1 < nkt) ATTN_STAGE(kt + 1, cur ^ 1)

        // S^T = K Q^T : per wave 64 keys x 16 q
        f32x4 sacc[4] = {};
        __builtin_amdgcn_s_setprio(1);
#pragma unroll
        for (int kc = 0; kc < 4; ++kc) {
            const int slot = ((kc * 4 + lq) & 8) | (((kc * 4 + lq) & 7) ^ (lm & 7));
#pragma unroll
            for (int mt = 0; mt < 4; ++mt) {
                bf16x8 bk = *(const bf16x8*)&Ks[cur][((mt * 16 + lm) * 16 + slot) * 8];
                sacc[mt] = __builtin_amdgcn_mfma_f32_16x16x32_bf16(bk, qf[kc], sacc[mt], 0, 0, 0);
            }
        }
        __builtin_amdgcn_s_setprio(0);

        // scores (log2 domain); mask only on the diagonal tile
        const float sbase = slope2 * (float)(kt * 64 - qg);
        float sc[4][4];
        if (kt == qt) {
#pragma unroll
            for (int mt = 0; mt < 4; ++mt)
#pragma unroll
                for (int r = 0; r < 4; ++r) {
                    float s = sacc[mt][r] * scale2 + (sbase + foff[mt][r]);
                    sc[mt][r] = (kt * 64 + mt * 16 + lq * 4 + r <= qg) ? s : -3e38f;
                }
        } else {
#pragma unroll
            for (int mt = 0; mt < 4; ++mt)
#pragma unroll
                for (int r = 0; r < 4; ++r)
                    sc[mt][r] = sacc[mt][r] * scale2 + (sbase + foff[mt][r]);
        }

        // row max: 15 in-lane + 2 shuffles
        float tm = sc[0][0];
#pragma unroll
        for (int mt = 0; mt < 4; ++mt)
#pragma unroll
            for (int r = 0; r < 4; ++r) tm = fmaxf(tm, sc[mt][r]);
        tm = fmaxf(tm, __shfl_xor(tm, 16));
        tm = fmaxf(tm, __shfl_xor(tm, 32));

        // defer-max (T13): if no row's max grew by >8 (log2), keep old max and
        // skip the O-rescale entirely (P bounded by 2^8 -> fine in bf16).
        const bool noresc = __all(tm <= mrow + 8.0f) && (kt > 0);
        float mnew, alpha;
        if (noresc) {
            mnew = mrow;
            alpha = 1.0f;
        } else {
            mnew = fmaxf(mrow, tm);
            alpha = __builtin_amdgcn_exp2f(mrow - mnew);
        }
        mrow = mnew;

        // p = exp2(sc - m) -> Ps[q][key], sum
        float psum = 0.0f;
#pragma unroll
        for (int mt = 0; mt < 4; ++mt) {
            float p0 = __builtin_amdgcn_exp2f(sc[mt][0] - mnew);
            float p1 = __builtin_amdgcn_exp2f(sc[mt][1] - mnew);
            float p2 = __builtin_amdgcn_exp2f(sc[mt][2] - mnew);
            float p3 = __builtin_amdgcn_exp2f(sc[mt][3] - mnew);
            psum += (p0 + p1) + (p2 + p3);
            uint2 wv;
            wv.x = ((unsigned)f2bf(p1) << 16) | f2bf(p0);
            wv.y = ((unsigned)f2bf(p3) << 16) | f2bf(p2);
            *(uint2*)&Ps[w][lm * 72 + mt * 16 + lq * 4] = wv;
        }
        psum += __shfl_xor(psum, 16);
        psum += __shfl_xor(psum, 32);
        lrow = lrow * alpha + psum;

        // rescale O (skipped when deferred; branch is wave-uniform)
        if (!noresc) {
            float av[4];
#pragma unroll
            for (int r = 0; r < 4; ++r) av[r] = __shfl(alpha, lq * 4 + r);
#pragma unroll
            for (int nt = 0; nt < 8; ++nt)
#pragma unroll
                for (int r = 0; r < 4; ++r) O[nt][r] *= av[r];
        }

        // PV: A = P (q=lane&15), B = V^T (swizzled)
        asm volatile("s_waitcnt lgkmcnt(0)" ::: "memory");
        __builtin_amdgcn_s_setprio(1);
#pragma unroll
        for (int kc2 = 0; kc2 < 2; ++kc2) {
            bf16x8 ap = *(const bf16x8*)&Ps[w][lm * 72 + kc2 * 32 + lq * 8];
            const int slot = (kc2 * 4 + lq) ^ (lm & 7);
#pragma unroll
            for (int nt = 0; nt < 8; ++nt) {
                bf16x8 bv = *(const bf16x8*)&Vs[cur][((nt * 16 + lm) * 8 + slot) * 8];
                O[nt] = __builtin_amdgcn_mfma_f32_16x16x32_bf16(ap, bv, O[nt], 0, 0, 0);
            }
        }
        __builtin_amdgcn_s_setprio(0);

        // single barrier per iteration: implicit vmcnt(0) drains the prefetch
        // (which had the whole compute phase to land) + syncs buffer reuse
        __syncthreads();
    }

    // epilogue
    float lb[4];
#pragma unroll
    for (int r = 0; r < 4; ++r)
        lb[r] = __builtin_amdgcn_rcpf(__shfl(lrow, lq * 4 + r));
    const int b = bh >> 4;
#pragma unroll
    for (int nt = 0; nt < 8; ++nt)
#pragma unroll
        for (int r = 0; r < 4; ++r) {
            int s = qbase + w * 16 + lq * 4 + r;
            int d = nt * 16 + lm;
            ob[((size_t)(b * SEQ + s)) * HID + h * HD + d] = f2bf(O[nt][r] * lb[r]);
        }
#undef ATTN_STAGE
}

// ---------------------------------------------------------------------------
extern "C" void kernel_launch(void* const* d_in, const int* in_sizes, int n_in,
                              void* d_out, int out_size, void* d_ws, size_t ws_size,
                              hipStream_t stream) {
    const float* hidden = (const float*)d_in[0];
    const float* w_qkv = (const float*)d_in[1];
    const float* b_qkv = (const float*)d_in[2];
    const float* w_proj = (const float*)d_in[3];
    const float* b_proj = (const float*)d_in[4];
    float* out = (float*)d_out;

    char* ws = (char*)d_ws;
    size_t off = 0;
    ushort_t* wqkvT = (ushort_t*)(ws + off); off += (size_t)NQKV * HID * 2;
    ushort_t* wprojT = (ushort_t*)(ws + off); off += (size_t)HID * HID * 2;
    ushort_t* hbf = (ushort_t*)(ws + off); off += (size_t)BATCH * SEQ * HID * 2;
    ushort_t* qw = (ushort_t*)(ws + off); off += (size_t)BATCH * NH * SEQ * HD * 2;
    ushort_t* kw = (ushort_t*)(ws + off); off += (size_t)BATCH * NH * SEQ * HD * 2;
    ushort_t* vTw = (ushort_t*)(ws + off); off += (size_t)BATCH * NH * SEQ * HD * 2;
    ushort_t* attnw = (ushort_t*)(ws + off); off += (size_t)BATCH * SEQ * HID * 2;

    to_bf16<<<dim3(BATCH * SEQ * HID / 8 / 256), 256, 0, stream>>>(
        hidden, hbf, BATCH * SEQ * HID / 8);
    transpose_to_bf16<<<dim3(NQKV / 32, HID / 32), dim3(32, 8), 0, stream>>>(
        w_qkv, wqkvT, HID, NQKV);
    transpose_to_bf16<<<dim3(HID / 32, HID / 32), dim3(32, 8), 0, stream>>>(
        w_proj, wprojT, HID, HID);

    gemm_qkv<<<dim3(BATCH * SEQ / 128, NQKV / 128), 256, 0, stream>>>(
        hbf, wqkvT, b_qkv, qw, kw, vTw);

    attn_kernel<<<dim3(BATCH * NH * 32), 256, 0, stream>>>(qw, kw, vTw, attnw);

    gemm_proj<<<dim3(BATCH * SEQ / 128, HID / 128), 256, 0, stream>>>(
        attnw, wprojT, b_proj, out);
}